// Round 9
// baseline (2117.022 us; speedup 1.0000x reference)
//
#include <hip/hip_runtime.h>
#include <stdint.h>

typedef uint32_t u32;
typedef uint16_t u16;
typedef __attribute__((ext_vector_type(8))) short bf16x8;
typedef __attribute__((ext_vector_type(4))) float f32x4;

__device__ __forceinline__ u16 f2bf(float f) {
  u32 u = __builtin_bit_cast(u32, f);
  return (u16)((u + 0x7FFFu + ((u >> 16) & 1u)) >> 16);
}
__device__ __forceinline__ u32 pack2bf(float a, float b) {
  return (u32)f2bf(a) | ((u32)f2bf(b) << 16);
}
__device__ __forceinline__ uint4 pack8bf(float4 a, float4 b) {
  uint4 r;
  r.x = pack2bf(a.x, a.y); r.y = pack2bf(a.z, a.w);
  r.z = pack2bf(b.x, b.y); r.w = pack2bf(b.z, b.w);
  return r;
}
__device__ __forceinline__ float sigmoid_(float x) { return 1.0f / (1.0f + __expf(-x)); }
__device__ __forceinline__ float tanh_(float x) { return 1.0f - 2.0f / (1.0f + __expf(2.0f * x)); }

// ---------------------------------------------------------------------------
// Persistent LSTM.
// [R9] post-mortem R8: TLP falsified cleanly — occupancy doubled (11.5->21.8)
//  yet +46% time, FETCH +84%: all chains are PHASE-LOCKED, so co-resident
//  WGs are always in the same phase (poll/burst/compute together) -> extra
//  occupancy only adds contention. R3 (1274us) = strong local optimum; the
//  workload is serial-chain-latency-bound.
// [R9 change, ON TOP OF EXACT R3]: delete the LDS staging hop. Each lane's
//  16 MFMA B-fragments are its own 16 contiguous-16B global slices
//  (h_row(n)[ks*32+q*8]). Load them DIRECTLY to registers: one base VGPR +
//  16 x global_load_dwordx4 offset:ks*64 sc0 sc1 (L1/L2 bypass mandatory:
//  consumer's own L2 holds stale same-parity lines from step t-2), then
//  MFMA straight from registers. Removes from the serial chain: LDS write,
//  BARRIER #1 entirely, 16 ds_reads (+4.1e7 bank conflicts). Cost: 4x L3
//  read amplification (wave reads full 16KB; 16MB/step device-wide) —
//  accepted deliberately: R5/R6 proved burst size was not binding.
//  h values fed to MFMA bit-identical to R3 -> absmax 0.0078125 must
//  reproduce. Flags/stores/poll EXACTLY R3.
// ---------------------------------------------------------------------------
__global__ __launch_bounds__(256, 1) void lstm_kernel(
    const int* __restrict__ trg, const float* __restrict__ w_ih,
    const float* __restrict__ w_hh, const float* __restrict__ b_ih,
    const float* __restrict__ b_hh, u16* __restrict__ h_buf,
    int* __restrict__ flags) {
  __shared__ float Xl[16 * 513];   // x inputs: [n 16][t 512+1 pad] f32
  __shared__ u32 Hs[256];          // h(t) gather: [n 16][u32pos 16]
  const int tid = threadIdx.x;
  const int wave = tid >> 6, lane = tid & 63;
  const int q = lane >> 4, n = lane & 15;
  const int bg = blockIdx.x & 15, ug = blockIdx.x >> 4;

  // ---- preload x = (float)trg for this bg's 16 batches ----
  #pragma unroll
  for (int c = 0; c < 4; ++c) {
    int e = c * 2048 + tid * 8;
    int rn = e >> 9, t0 = e & 511;
    const int* src = trg + (bg * 16 + rn) * 512 + t0;
    int4 a = *(const int4*)src;
    int4 b = *(const int4*)(src + 4);
    float* dst = &Xl[rn * 513 + t0];
    dst[0] = (float)a.x; dst[1] = (float)a.y; dst[2] = (float)a.z; dst[3] = (float)a.w;
    dst[4] = (float)b.x; dst[5] = (float)b.y; dst[6] = (float)b.z; dst[7] = (float)b.w;
  }

  // ---- preload w_hh slice: tile-interleaved rows, NATURAL k packing ----
  // A-row rit of tile i -> gate rit&3, unit ug*32 + wave*8 + 2*(rit>>2) + i
  bf16x8 Areg[2][16];
  const int rit = lane & 15;
  #pragma unroll
  for (int i = 0; i < 2; ++i) {
    int grow = (rit & 3) * 512 + ug * 32 + wave * 8 + 2 * (rit >> 2) + i;
    const float* wr = w_hh + (size_t)grow * 512;
    #pragma unroll
    for (int ks = 0; ks < 16; ++ks) {
      const float* p = wr + ks * 32 + q * 8;
      float4 f0 = *(const float4*)p;
      float4 f1 = *(const float4*)(p + 4);
      Areg[i][ks] = __builtin_bit_cast(bf16x8, pack8bf(f0, f1));
    }
  }

  // per-lane input weights & bias: lane q, tile i -> unit ug*32 + wave*8 + 2q+i
  float wi[2][4], bs[2][4];
  #pragma unroll
  for (int i = 0; i < 2; ++i) {
    #pragma unroll
    for (int r = 0; r < 4; ++r) {
      int grow = r * 512 + ug * 32 + wave * 8 + q * 2 + i;
      wi[i][r] = w_ih[grow];
      bs[i][r] = b_ih[grow] + b_hh[grow];
    }
  }
  float cst[2] = {0.f, 0.f};  // cell: units ug*32+wave*8+2q+{0,1}, batch bg*16+n
  __syncthreads();

  for (int t = 1; t <= 511; ++t) {
    // ---- wait for h(t-1): all lanes poll the per-bg per-t counter (ONE
    //      line, wave-coalesced broadcast load). 16 producers. EXACT R3. ----
    if (t > 1) {
      int cnt = 0;
      while (__hip_atomic_load(&flags[bg * 512 + (t - 1)], __ATOMIC_RELAXED,
                               __HIP_MEMORY_SCOPE_AGENT) < 16) {
        if (++cnt > (1 << 22)) break;  // convert deadlock into wrong answer
      }
    }
    // ---- direct global->reg: this lane's 16 B-fragments of h(t-1).
    //      base = row n, bytes q*16; fragment ks at +ks*64 bytes. ----
    uint4 d0, d1, d2, d3, d4, d5, d6, d7, d8, d9, d10, d11, d12, d13, d14, d15;
    {
      const u16* base = h_buf + (size_t)(((t - 1) & 1) * 16 + bg) * 8192 +
                        n * 512 + q * 8;
      asm volatile(
          "global_load_dwordx4 %0, %16, off sc0 sc1\n\t"
          "global_load_dwordx4 %1, %16, off offset:64 sc0 sc1\n\t"
          "global_load_dwordx4 %2, %16, off offset:128 sc0 sc1\n\t"
          "global_load_dwordx4 %3, %16, off offset:192 sc0 sc1\n\t"
          "global_load_dwordx4 %4, %16, off offset:256 sc0 sc1\n\t"
          "global_load_dwordx4 %5, %16, off offset:320 sc0 sc1\n\t"
          "global_load_dwordx4 %6, %16, off offset:384 sc0 sc1\n\t"
          "global_load_dwordx4 %7, %16, off offset:448 sc0 sc1\n\t"
          "global_load_dwordx4 %8, %16, off offset:512 sc0 sc1\n\t"
          "global_load_dwordx4 %9, %16, off offset:576 sc0 sc1\n\t"
          "global_load_dwordx4 %10, %16, off offset:640 sc0 sc1\n\t"
          "global_load_dwordx4 %11, %16, off offset:704 sc0 sc1\n\t"
          "global_load_dwordx4 %12, %16, off offset:768 sc0 sc1\n\t"
          "global_load_dwordx4 %13, %16, off offset:832 sc0 sc1\n\t"
          "global_load_dwordx4 %14, %16, off offset:896 sc0 sc1\n\t"
          "global_load_dwordx4 %15, %16, off offset:960 sc0 sc1\n\t"
          "s_waitcnt vmcnt(0)"
          : "=&v"(d0), "=&v"(d1), "=&v"(d2), "=&v"(d3),
            "=&v"(d4), "=&v"(d5), "=&v"(d6), "=&v"(d7),
            "=&v"(d8), "=&v"(d9), "=&v"(d10), "=&v"(d11),
            "=&v"(d12), "=&v"(d13), "=&v"(d14), "=&v"(d15)
          : "v"(base)
          : "memory");
    }
    __builtin_amdgcn_sched_barrier(0);  // keep MFMAs after the vmcnt wait

    f32x4 acc[2] = {{0.f, 0.f, 0.f, 0.f}, {0.f, 0.f, 0.f, 0.f}};
    #pragma unroll
    for (int ks = 0; ks < 16; ++ks) {
      uint4 dk = (ks == 0) ? d0 : (ks == 1) ? d1 : (ks == 2) ? d2 :
                 (ks == 3) ? d3 : (ks == 4) ? d4 : (ks == 5) ? d5 :
                 (ks == 6) ? d6 : (ks == 7) ? d7 : (ks == 8) ? d8 :
                 (ks == 9) ? d9 : (ks == 10) ? d10 : (ks == 11) ? d11 :
                 (ks == 12) ? d12 : (ks == 13) ? d13 : (ks == 14) ? d14 : d15;
      bf16x8 bf = __builtin_bit_cast(bf16x8, dk);
      acc[0] = __builtin_amdgcn_mfma_f32_16x16x32_bf16(Areg[0][ks], bf, acc[0], 0, 0, 0);
      acc[1] = __builtin_amdgcn_mfma_f32_16x16x32_bf16(Areg[1][ks], bf, acc[1], 0, 0, 0);
    }

    float x = Xl[n * 513 + (t - 1)];
    float hv0, hv1;
    #pragma unroll
    for (int i = 0; i < 2; ++i) {
      float pi = acc[i][0] + x * wi[i][0] + bs[i][0];
      float pf = acc[i][1] + x * wi[i][1] + bs[i][1];
      float pg = acc[i][2] + x * wi[i][2] + bs[i][2];
      float po = acc[i][3] + x * wi[i][3] + bs[i][3];
      float ig = sigmoid_(pi), fg = sigmoid_(pf), og = sigmoid_(po);
      float gg = tanh_(pg);
      cst[i] = fg * cst[i] + ig * gg;
      float h = og * tanh_(cst[i]);
      if (i == 0) hv0 = h; else hv1 = h;
    }

    // ---- gather h(t) in LDS, then coalesced dword store (agent scope) ----
    Hs[n * 16 + wave * 4 + q] = pack2bf(hv0, hv1);  // units ug*32+wave*8+2q,+1
    __syncthreads();
    {
      u32 hv = Hs[tid];
      // u32 index: parity*65536 + (bg*16 + n')*256 + ug*16 + pos, n'=tid>>4
      u32* dst = (u32*)h_buf + (size_t)((t & 1) ? 65536 : 0) +
                 (size_t)(bg * 16 + (tid >> 4)) * 256 + ug * 16 + (tid & 15);
      asm volatile("global_store_dword %0, %1, off sc1\n\ts_waitcnt vmcnt(0)"
                   :: "v"(dst), "v"(hv) : "memory");
    }
    __syncthreads();  // all 256 stores drained before the flag add
    if (tid == 0) {
      __hip_atomic_fetch_add(&flags[bg * 512 + t], 1, __ATOMIC_RELAXED,
                             __HIP_MEMORY_SCOPE_AGENT);
    }
  }
}

// ---------------------------------------------------------------------------
// Head GEMM (R2's proven version): out[b][m] = sum_k A[m][k]*B[b][k] (+bias),
// A fp32 MxK, B bf16 [256][K]. M=128/WG, N=256. mode 0: relu+bf16 out (fc1),
// mode 1: fp32 out (fc2). Out leading dim == M for both uses.
// ---------------------------------------------------------------------------
__global__ __launch_bounds__(256, 1) void head_gemm(
    const float* __restrict__ A, const u16* __restrict__ B,
    const float* __restrict__ bias, void* __restrict__ outv,
    int M, int K, int mode) {
  __shared__ u16 Ach[128 * 40];
  __shared__ u16 Bch[256 * 40];
  const int tid = threadIdx.x;
  const int wave = tid >> 6, lane = tid & 63;
  const int q = lane >> 4, l15 = lane & 15;
  const int mblk = blockIdx.x * 128;
  const int nch = K >> 5;
  f32x4 acc[2][16];
  #pragma unroll
  for (int i = 0; i < 2; ++i)
    #pragma unroll
    for (int nb = 0; nb < 16; ++nb) acc[i][nb] = (f32x4){0.f, 0.f, 0.f, 0.f};

  for (int ch = 0; ch < nch; ++ch) {
    __syncthreads();
    {  // A chunk: 128 rows x 32 k, fp32 -> bf16
      int row = tid >> 1, k = (tid & 1) * 16;
      const float* src = A + (size_t)(mblk + row) * K + ch * 32 + k;
      float4 f0 = *(const float4*)src;
      float4 f1 = *(const float4*)(src + 4);
      float4 f2 = *(const float4*)(src + 8);
      float4 f3 = *(const float4*)(src + 12);
      u16* dst = &Ach[row * 40 + k];
      *(uint4*)dst = pack8bf(f0, f1);
      *(uint4*)(dst + 8) = pack8bf(f2, f3);
    }
    #pragma unroll
    for (int c = 0; c < 4; ++c) {  // B chunk: 256 rows x 32 k bf16
      int e = c * 2048 + tid * 8;
      int nr = e >> 5, k = e & 31;
      uint4 d = *(const uint4*)(B + (size_t)nr * K + ch * 32 + k);
      *(uint4*)&Bch[nr * 40 + k] = d;
    }
    __syncthreads();
    bf16x8 a0 = *(const bf16x8*)&Ach[((wave * 2 + 0) * 16 + l15) * 40 + q * 8];
    bf16x8 a1 = *(const bf16x8*)&Ach[((wave * 2 + 1) * 16 + l15) * 40 + q * 8];
    #pragma unroll
    for (int nb = 0; nb < 16; ++nb) {
      bf16x8 bf = *(const bf16x8*)&Bch[(nb * 16 + l15) * 40 + q * 8];
      acc[0][nb] = __builtin_amdgcn_mfma_f32_16x16x32_bf16(a0, bf, acc[0][nb], 0, 0, 0);
      acc[1][nb] = __builtin_amdgcn_mfma_f32_16x16x32_bf16(a1, bf, acc[1][nb], 0, 0, 0);
    }
  }
  #pragma unroll
  for (int i = 0; i < 2; ++i) {
    int j0 = mblk + (wave * 2 + i) * 16 + q * 4;
    float4 bv = *(const float4*)(bias + j0);
    #pragma unroll
    for (int nb = 0; nb < 16; ++nb) {
      int b = nb * 16 + l15;
      f32x4 v = acc[i][nb];
      v[0] += bv.x; v[1] += bv.y; v[2] += bv.z; v[3] += bv.w;
      if (mode == 0) {
        v[0] = fmaxf(v[0], 0.f); v[1] = fmaxf(v[1], 0.f);
        v[2] = fmaxf(v[2], 0.f); v[3] = fmaxf(v[3], 0.f);
        u16* z = (u16*)outv;
        uint2 pk;
        pk.x = pack2bf(v[0], v[1]);
        pk.y = pack2bf(v[2], v[3]);
        *(uint2*)(z + (size_t)b * M + j0) = pk;
      } else {
        float* op = (float*)outv + (size_t)b * M + j0;
        float4 o;
        o.x = v[0]; o.y = v[1]; o.z = v[2]; o.w = v[3];
        *(float4*)op = o;
      }
    }
  }
}

// ---------------------------------------------------------------------------
// Workspace layout (bytes):
//   [0,        524288)  h_buf: [parity 2][bg 16][n 16][k 512] bf16, natural
//   [524288,   557056)  flags: [bg 16][t 512] int, count of finished WGs
//   [557056,  1081344)  z: [256][1024] bf16
// ---------------------------------------------------------------------------
extern "C" void kernel_launch(void* const* d_in, const int* in_sizes, int n_in,
                              void* d_out, int out_size, void* d_ws, size_t ws_size,
                              hipStream_t stream) {
  (void)in_sizes; (void)n_in; (void)out_size; (void)ws_size;
  const int* trg = (const int*)d_in[2];
  const float* w_ih = (const float*)d_in[3];
  const float* w_hh = (const float*)d_in[4];
  const float* b_ih = (const float*)d_in[5];
  const float* b_hh = (const float*)d_in[6];
  const float* fc1_w = (const float*)d_in[7];
  const float* fc1_b = (const float*)d_in[8];
  const float* fc2_w = (const float*)d_in[9];
  const float* fc2_b = (const float*)d_in[10];

  u16* h_buf = (u16*)d_ws;
  int* flags = (int*)((char*)d_ws + 524288);
  u16* z = (u16*)((char*)d_ws + 557056);

  hipMemsetAsync(d_ws, 0, 262144, stream);                  // h parity 0 = h(0) = 0
  hipMemsetAsync((char*)d_ws + 524288, 0, 32768, stream);   // flags = 0

  lstm_kernel<<<256, 256, 0, stream>>>(trg, w_ih, w_hh, b_ih, b_hh, h_buf, flags);

  const u16* h_final = h_buf + 131072;  // parity 1 == h(511), layout [b][512]
  head_gemm<<<8, 256, 0, stream>>>(fc1_w, h_final, fc1_b, (void*)z, 1024, 512, 0);
  head_gemm<<<250, 256, 0, stream>>>(fc2_w, z, fc2_b, d_out, 32000, 1024, 1);
}

// Round 10
// 1816.256 us; speedup vs baseline: 1.1656x; 1.1656x over previous
//
#include <hip/hip_runtime.h>
#include <stdint.h>

typedef uint32_t u32;
typedef uint16_t u16;
typedef __attribute__((ext_vector_type(8))) short bf16x8;
typedef __attribute__((ext_vector_type(4))) float f32x4;

__device__ __forceinline__ u16 f2bf(float f) {
  u32 u = __builtin_bit_cast(u32, f);
  return (u16)((u + 0x7FFFu + ((u >> 16) & 1u)) >> 16);
}
__device__ __forceinline__ u32 pack2bf(float a, float b) {
  return (u32)f2bf(a) | ((u32)f2bf(b) << 16);
}
__device__ __forceinline__ uint4 pack8bf(float4 a, float4 b) {
  uint4 r;
  r.x = pack2bf(a.x, a.y); r.y = pack2bf(a.z, a.w);
  r.z = pack2bf(b.x, b.y); r.w = pack2bf(b.z, b.w);
  return r;
}
__device__ __forceinline__ float sigmoid_(float x) { return 1.0f / (1.0f + __expf(-x)); }
__device__ __forceinline__ float tanh_(float x) { return 1.0f - 2.0f / (1.0f + __expf(2.0f * x)); }

// ---------------------------------------------------------------------------
// Persistent LSTM — CHAMPION (Round-3 bench: lstm 1274-1285us, absmax
// 0.0078125). Byte-exact revert. Post-mortems R4/R5/R6/R8/R9: every
// structural deviation regressed —
//  R4 per-producer flags: +7% (16x poll-line fanout);
//  R5 1024-thr: 3.3x (VGPR spill at 16 waves/CU);
//  R6 8 producers + 2x work/wave: +33% (exposed serial latency);
//  R8 2x TLP: +46% (phase-locked chains -> contention only);
//  R9 direct global->reg MFMA feed: +47% (4x L3 read amplification, sc0/sc1
//     bypass means L2 absorbs nothing; 4MB/step sits at the L3 knee).
// Conclusion: this structure is at a latency/L3-throughput local optimum;
// LSTM frozen. This round only touches the head GEMMs.
// ---------------------------------------------------------------------------
__global__ __launch_bounds__(256, 2) void lstm_kernel(
    const int* __restrict__ trg, const float* __restrict__ w_ih,
    const float* __restrict__ w_hh, const float* __restrict__ b_ih,
    const float* __restrict__ b_hh, u16* __restrict__ h_buf,
    int* __restrict__ flags) {
  __shared__ u16 Bb[16 * 520];     // h(t-1): [n 16][k 512+8 pad] bf16
  __shared__ float Xl[16 * 513];   // x inputs: [n 16][t 512+1 pad] f32
  __shared__ u32 Hs[256];          // h(t) gather: [n 16][u32pos 16]
  const int tid = threadIdx.x;
  const int wave = tid >> 6, lane = tid & 63;
  const int q = lane >> 4, n = lane & 15;
  const int bg = blockIdx.x & 15, ug = blockIdx.x >> 4;

  // ---- preload x = (float)trg for this bg's 16 batches ----
  #pragma unroll
  for (int c = 0; c < 4; ++c) {
    int e = c * 2048 + tid * 8;
    int rn = e >> 9, t0 = e & 511;
    const int* src = trg + (bg * 16 + rn) * 512 + t0;
    int4 a = *(const int4*)src;
    int4 b = *(const int4*)(src + 4);
    float* dst = &Xl[rn * 513 + t0];
    dst[0] = (float)a.x; dst[1] = (float)a.y; dst[2] = (float)a.z; dst[3] = (float)a.w;
    dst[4] = (float)b.x; dst[5] = (float)b.y; dst[6] = (float)b.z; dst[7] = (float)b.w;
  }

  // ---- preload w_hh slice: tile-interleaved rows, NATURAL k packing ----
  // A-row rit of tile i -> gate rit&3, unit ug*32 + wave*8 + 2*(rit>>2) + i
  bf16x8 Areg[2][16];
  const int rit = lane & 15;
  #pragma unroll
  for (int i = 0; i < 2; ++i) {
    int grow = (rit & 3) * 512 + ug * 32 + wave * 8 + 2 * (rit >> 2) + i;
    const float* wr = w_hh + (size_t)grow * 512;
    #pragma unroll
    for (int ks = 0; ks < 16; ++ks) {
      const float* p = wr + ks * 32 + q * 8;
      float4 f0 = *(const float4*)p;
      float4 f1 = *(const float4*)(p + 4);
      Areg[i][ks] = __builtin_bit_cast(bf16x8, pack8bf(f0, f1));
    }
  }

  // per-lane input weights & bias: lane q, tile i -> unit wave*8 + 2q + i
  float wi[2][4], bs[2][4];
  #pragma unroll
  for (int i = 0; i < 2; ++i) {
    #pragma unroll
    for (int r = 0; r < 4; ++r) {
      int grow = r * 512 + ug * 32 + wave * 8 + q * 2 + i;
      wi[i][r] = w_ih[grow];
      bs[i][r] = b_ih[grow] + b_hh[grow];
    }
  }
  float cst[2] = {0.f, 0.f};  // cell state: units wave*8+2q+{0,1}, batch bg*16+n
  __syncthreads();

  for (int t = 1; t <= 511; ++t) {
    // ---- wait for h(t-1) published: ALL lanes poll (wave-coalesced
    //      same-address load). No barrier: each thread's staging load is
    //      program-ordered after its own poll success. Per-bg flag line. ----
    if (t > 1) {
      int cnt = 0;
      while (__hip_atomic_load(&flags[bg * 512 + (t - 1)], __ATOMIC_RELAXED,
                               __HIP_MEMORY_SCOPE_AGENT) < 16) {
        if (++cnt > (1 << 22)) break;  // convert deadlock into wrong answer
      }
    }
    // ---- stage B = h(t-1)[512 x 16] for this bg (16KB) from L3 ----
    {
      const u16* src = h_buf + (size_t)(((t - 1) & 1) * 16 + bg) * 8192;
      const u16* p0 = src + 0 * 2048 + tid * 8;
      const u16* p1 = src + 1 * 2048 + tid * 8;
      const u16* p2 = src + 2 * 2048 + tid * 8;
      const u16* p3 = src + 3 * 2048 + tid * 8;
      uint4 d0, d1, d2, d3;
      asm volatile(
          "global_load_dwordx4 %0, %4, off sc0 sc1\n\t"
          "global_load_dwordx4 %1, %5, off sc0 sc1\n\t"
          "global_load_dwordx4 %2, %6, off sc0 sc1\n\t"
          "global_load_dwordx4 %3, %7, off sc0 sc1\n\t"
          "s_waitcnt vmcnt(0)"
          : "=&v"(d0), "=&v"(d1), "=&v"(d2), "=&v"(d3)
          : "v"(p0), "v"(p1), "v"(p2), "v"(p3)
          : "memory");
      #pragma unroll
      for (int c = 0; c < 4; ++c) {
        int e = c * 2048 + tid * 8;
        int rn = e >> 9, k = e & 511;
        uint4 d = (c == 0) ? d0 : (c == 1) ? d1 : (c == 2) ? d2 : d3;
        *(uint4*)&Bb[rn * 520 + k] = d;
      }
    }
    __syncthreads();

    f32x4 acc[2] = {{0.f, 0.f, 0.f, 0.f}, {0.f, 0.f, 0.f, 0.f}};
    const u16* brow = &Bb[n * 520];
    #pragma unroll
    for (int ks = 0; ks < 16; ++ks) {
      bf16x8 bf = *(const bf16x8*)(brow + ks * 32 + q * 8);
      acc[0] = __builtin_amdgcn_mfma_f32_16x16x32_bf16(Areg[0][ks], bf, acc[0], 0, 0, 0);
      acc[1] = __builtin_amdgcn_mfma_f32_16x16x32_bf16(Areg[1][ks], bf, acc[1], 0, 0, 0);
    }

    float x = Xl[n * 513 + (t - 1)];
    float hv0, hv1;
    #pragma unroll
    for (int i = 0; i < 2; ++i) {
      float pi = acc[i][0] + x * wi[i][0] + bs[i][0];
      float pf = acc[i][1] + x * wi[i][1] + bs[i][1];
      float pg = acc[i][2] + x * wi[i][2] + bs[i][2];
      float po = acc[i][3] + x * wi[i][3] + bs[i][3];
      float ig = sigmoid_(pi), fg = sigmoid_(pf), og = sigmoid_(po);
      float gg = tanh_(pg);
      cst[i] = fg * cst[i] + ig * gg;
      float h = og * tanh_(cst[i]);
      if (i == 0) hv0 = h; else hv1 = h;
    }

    // ---- gather h(t) in LDS, then coalesced dword store (agent scope) ----
    Hs[n * 16 + wave * 4 + q] = pack2bf(hv0, hv1);  // units wave*8+2q, +1
    __syncthreads();
    {
      u32 hv = Hs[tid];
      // u32 index: parity*65536 + (bg*16 + n')*256 + ug*16 + pos, n'=tid>>4
      u32* dst = (u32*)h_buf + (size_t)((t & 1) ? 65536 : 0) +
                 (size_t)(bg * 16 + (tid >> 4)) * 256 + ug * 16 + (tid & 15);
      asm volatile("global_store_dword %0, %1, off sc1\n\ts_waitcnt vmcnt(0)"
                   :: "v"(dst), "v"(hv) : "memory");
    }
    __syncthreads();  // all 256 stores drained before the flag add
    if (tid == 0) {
      __hip_atomic_fetch_add(&flags[bg * 512 + t], 1, __ATOMIC_RELAXED,
                             __HIP_MEMORY_SCOPE_AGENT);
    }
  }
}

// ---------------------------------------------------------------------------
// Head GEMM, R10 retile: M=64/WG (ONE 16-row tile per wave) instead of 128.
//  Rationale: fc2 at 250 WGs = 1 WG/CU, 2 barriers per 32-k chunk -> HBM
//  stage latency (~900cy) exposed 32x; head measured ~220us vs ~30us
//  roofline. M=64 -> fc2 grid 500 = 2 WGs/CU (launch_bounds(256,2), LDS
//  25.6KB, acc 64 VGPR): co-resident WGs are NOT phase-locked (independent),
//  so they hide each other's stage latency. fc1 grid 8 -> 16.
//  Per-output math and staging order per row unchanged -> out BIT-IDENTICAL.
// out[b][m] = sum_k A[m][k]*B[b][k] (+bias); A fp32 MxK, B bf16 [256][K].
// mode 0: relu+bf16 out (fc1), mode 1: fp32 out (fc2). Out ld == M.
// ---------------------------------------------------------------------------
__global__ __launch_bounds__(256, 2) void head_gemm(
    const float* __restrict__ A, const u16* __restrict__ B,
    const float* __restrict__ bias, void* __restrict__ outv,
    int M, int K, int mode) {
  __shared__ u16 Ach[64 * 40];
  __shared__ u16 Bch[256 * 40];
  const int tid = threadIdx.x;
  const int wave = tid >> 6, lane = tid & 63;
  const int q = lane >> 4, l15 = lane & 15;
  const int mblk = blockIdx.x * 64;
  const int nch = K >> 5;
  f32x4 acc[16];
  #pragma unroll
  for (int nb = 0; nb < 16; ++nb) acc[nb] = (f32x4){0.f, 0.f, 0.f, 0.f};

  for (int ch = 0; ch < nch; ++ch) {
    __syncthreads();
    {  // A chunk: 64 rows x 32 k, fp32 -> bf16 (8 floats = 16B bf16 / thread)
      int e = tid * 8;
      int row = e >> 5, k = e & 31;
      const float* src = A + (size_t)(mblk + row) * K + ch * 32 + k;
      float4 f0 = *(const float4*)src;
      float4 f1 = *(const float4*)(src + 4);
      *(uint4*)&Ach[row * 40 + k] = pack8bf(f0, f1);
    }
    #pragma unroll
    for (int c = 0; c < 4; ++c) {  // B chunk: 256 rows x 32 k bf16
      int e = c * 2048 + tid * 8;
      int nr = e >> 5, k = e & 31;
      uint4 d = *(const uint4*)(B + (size_t)nr * K + ch * 32 + k);
      *(uint4*)&Bch[nr * 40 + k] = d;
    }
    __syncthreads();
    bf16x8 a0 = *(const bf16x8*)&Ach[(wave * 16 + l15) * 40 + q * 8];
    #pragma unroll
    for (int nb = 0; nb < 16; ++nb) {
      bf16x8 bf = *(const bf16x8*)&Bch[(nb * 16 + l15) * 40 + q * 8];
      acc[nb] = __builtin_amdgcn_mfma_f32_16x16x32_bf16(a0, bf, acc[nb], 0, 0, 0);
    }
  }
  {
    int j0 = mblk + wave * 16 + q * 4;
    float4 bv = *(const float4*)(bias + j0);
    #pragma unroll
    for (int nb = 0; nb < 16; ++nb) {
      int b = nb * 16 + l15;
      f32x4 v = acc[nb];
      v[0] += bv.x; v[1] += bv.y; v[2] += bv.z; v[3] += bv.w;
      if (mode == 0) {
        v[0] = fmaxf(v[0], 0.f); v[1] = fmaxf(v[1], 0.f);
        v[2] = fmaxf(v[2], 0.f); v[3] = fmaxf(v[3], 0.f);
        u16* z = (u16*)outv;
        uint2 pk;
        pk.x = pack2bf(v[0], v[1]);
        pk.y = pack2bf(v[2], v[3]);
        *(uint2*)(z + (size_t)b * M + j0) = pk;
      } else {
        float* op = (float*)outv + (size_t)b * M + j0;
        float4 o;
        o.x = v[0]; o.y = v[1]; o.z = v[2]; o.w = v[3];
        *(float4*)op = o;
      }
    }
  }
}

// ---------------------------------------------------------------------------
// Workspace layout (bytes):
//   [0,        524288)  h_buf: [parity 2][bg 16][n 16][k 512] bf16, natural
//   [524288,   557056)  flags: [bg 16][t 512] int, count of finished WGs
//   [557056,  1081344)  z: [256][1024] bf16
// ---------------------------------------------------------------------------
extern "C" void kernel_launch(void* const* d_in, const int* in_sizes, int n_in,
                              void* d_out, int out_size, void* d_ws, size_t ws_size,
                              hipStream_t stream) {
  (void)in_sizes; (void)n_in; (void)out_size; (void)ws_size;
  const int* trg = (const int*)d_in[2];
  const float* w_ih = (const float*)d_in[3];
  const float* w_hh = (const float*)d_in[4];
  const float* b_ih = (const float*)d_in[5];
  const float* b_hh = (const float*)d_in[6];
  const float* fc1_w = (const float*)d_in[7];
  const float* fc1_b = (const float*)d_in[8];
  const float* fc2_w = (const float*)d_in[9];
  const float* fc2_b = (const float*)d_in[10];

  u16* h_buf = (u16*)d_ws;
  int* flags = (int*)((char*)d_ws + 524288);
  u16* z = (u16*)((char*)d_ws + 557056);

  hipMemsetAsync(d_ws, 0, 262144, stream);                  // h parity 0 = h(0) = 0
  hipMemsetAsync((char*)d_ws + 524288, 0, 32768, stream);   // flags = 0

  lstm_kernel<<<256, 256, 0, stream>>>(trg, w_ih, w_hh, b_ih, b_hh, h_buf, flags);

  const u16* h_final = h_buf + 131072;  // parity 1 == h(511), layout [b][512]
  head_gemm<<<16, 256, 0, stream>>>(fc1_w, h_final, fc1_b, (void*)z, 1024, 512, 0);
  head_gemm<<<500, 256, 0, stream>>>(fc2_w, z, fc2_b, d_out, 32000, 1024, 1);
}